// Round 5
// baseline (1019.579 us; speedup 1.0000x reference)
//
#include <hip/hip_runtime.h>
#include <hip/hip_bf16.h>

#define BB 8192
#define TT 64
#define L2E 1.44269504088896f

typedef __attribute__((ext_vector_type(8))) short bf16x8;
typedef __attribute__((ext_vector_type(4))) float f32x4;

__device__ __forceinline__ float exp2g(float x) { return __builtin_amdgcn_exp2f(x); }
__device__ __forceinline__ float rcpg(float x)  { return __builtin_amdgcn_rcpf(x); }
__device__ __forceinline__ short f2bf_s(float x) {
  __hip_bfloat16 b = __float2bfloat16(x);
  return *reinterpret_cast<short*>(&b);
}
// acts[row][k], k in [0,512): e_buf0, e_buf1, h_buf0, h_buf1. 16B-granule XOR swizzle.
__device__ __forceinline__ int aidx(int row, int k) {
  return row * 512 + ((((k >> 3) ^ (row & 7))) << 3) + (k & 7);
}

// ---- 1. weights -> bf16 MFMA-fragment order, exp2-prescaled; bc = (b_ih+b_hh)*scale ----
__global__ void prep_kernel(const float* __restrict__ Wih, const float* __restrict__ Whh,
                            const float* __restrict__ bih, const float* __restrict__ bhh,
                            const float* __restrict__ Wout,
                            short* __restrict__ Wcb, short* __restrict__ Woutb,
                            float* __restrict__ bc) {
  int idx = blockIdx.x * 256 + threadIdx.x;   // 17152 total
  if (idx < 16384) {
    int l = idx & 63, f = idx >> 6;
    int kt = f >> 5, nt = f & 31;
    int k0 = kt * 32 + ((l >> 4) << 3);
    int col = nt * 16 + (l & 15);
    int gate = col >> 7;
    float s = (gate == 2) ? (2.f * L2E) : (-L2E);
    const float* src = (k0 < 128) ? (Wih + col * 128 + k0) : (Whh + col * 128 + (k0 - 128));
    bf16x8 v;
    #pragma unroll
    for (int e = 0; e < 8; e++) v[e] = f2bf_s(src[e] * s);
    *(bf16x8*)(Wcb + (size_t)idx * 8) = v;
  } else if (idx < 16640) {
    int i2 = idx - 16384;
    int l = i2 & 63, f = i2 >> 6;              // f = kyt
    int k0 = f * 32 + ((l >> 4) << 3);
    int col = l & 15;
    bf16x8 v;
    #pragma unroll
    for (int e = 0; e < 8; e++)
      v[e] = (col < 5) ? f2bf_s(Wout[col * 128 + k0 + e]) : (short)0;
    *(bf16x8*)(Woutb + (size_t)i2 * 8) = v;
  } else {
    int i3 = idx - 16640;
    int gate = i3 >> 7;
    float s = (gate == 2) ? (2.f * L2E) : (-L2E);
    bc[i3] = (bih[i3] + bhh[i3]) * s;
  }
}

// ---- 2. per-t raw input moments over batch ----
__global__ void stats_kernel(const float* __restrict__ x, float* __restrict__ stats) {
  int t = blockIdx.x, tid = threadIdx.x;
  float s0=0, s1=0, s2=0, s3=0, s4=0;
  for (int b = tid; b < BB; b += 256) {
    const float* p = x + ((size_t)b * TT + t) * 2;
    float x0 = p[0], x1 = p[1];
    s0 += x0; s1 += x1; s2 += x0*x0; s3 += x0*x1; s4 += x1*x1;
  }
  __shared__ float red[4][5];
  int lane = tid & 63, w = tid >> 6;
  #pragma unroll
  for (int off = 32; off > 0; off >>= 1) {
    s0 += __shfl_down(s0, off); s1 += __shfl_down(s1, off);
    s2 += __shfl_down(s2, off); s3 += __shfl_down(s3, off); s4 += __shfl_down(s4, off);
  }
  if (lane == 0) { red[w][0]=s0; red[w][1]=s1; red[w][2]=s2; red[w][3]=s3; red[w][4]=s4; }
  __syncthreads();
  if (tid < 5) stats[t*5 + tid] = red[0][tid] + red[1][tid] + red[2][tid] + red[3][tid];
}

// ---- 3. fold input-BN + embed Linear + per-step embed-BN into A0/A1/C ----
__global__ void coef_kernel(const float* __restrict__ stats,
                            const float* __restrict__ Wemb, const float* __restrict__ bemb,
                            const float* __restrict__ ing, const float* __restrict__ inb,
                            const float* __restrict__ eg, const float* __restrict__ eb,
                            float* __restrict__ A0, float* __restrict__ A1, float* __restrict__ Ct) {
  __shared__ float st[64][5];
  __shared__ float glob[4];
  int tid = threadIdx.x;  // 128
  for (int i = tid; i < 320; i += 128) st[i / 5][i % 5] = stats[i];
  __syncthreads();
  if (tid == 0) {
    float S0=0, S1=0, S00=0, S11=0;
    for (int t = 0; t < 64; t++) { S0+=st[t][0]; S1+=st[t][1]; S00+=st[t][2]; S11+=st[t][4]; }
    float inv_n = 1.f / (float)(BB * TT);
    float M0 = S0*inv_n, M1 = S1*inv_n;
    float V0 = S00*inv_n - M0*M0, V1 = S11*inv_n - M1*M1;
    float P0 = rsqrtf(V0 + 1e-5f) * ing[0];
    float P1 = rsqrtf(V1 + 1e-5f) * ing[1];
    glob[0]=P0; glob[1]=P1; glob[2]=inb[0]-M0*P0; glob[3]=inb[1]-M1*P1;
  }
  __syncthreads();
  float P0=glob[0], P1=glob[1], Q0=glob[2], Q1=glob[3];
  int j = tid;
  float w0 = Wemb[j*2], w1 = Wemb[j*2+1];
  float a0 = P0*w0, a1 = P1*w1;
  float cj = Q0*w0 + Q1*w1 + bemb[j];
  float gam = eg[j], bet = eb[j];
  float invB = 1.f / (float)BB;
  for (int t = 0; t < 64; t++) {
    float m0 = st[t][0]*invB, m1 = st[t][1]*invB;
    float v00 = st[t][2]*invB - m0*m0;
    float v01 = st[t][3]*invB - m0*m1;
    float v11 = st[t][4]*invB - m1*m1;
    float mean = a0*m0 + a1*m1 + cj;
    float var  = a0*a0*v00 + 2.f*a0*a1*v01 + a1*a1*v11;
    float G = rsqrtf(var + 1e-5f) * gam;
    A0[t*128 + j] = G * a0;
    A1[t*128 + j] = G * a1;
    Ct[t*128 + j] = G * cj + (bet - mean * G);
  }
}

// ---- 4. MFMA recurrence: 512 blocks x 16 rows, 8 waves, 2 blocks/CU ----
__launch_bounds__(512, 4)
__global__ void lstm_kernel(const float* __restrict__ x,
                            const float* __restrict__ A0, const float* __restrict__ A1,
                            const float* __restrict__ Ctab,
                            const short* __restrict__ Wcb, const float* __restrict__ bc,
                            const short* __restrict__ Woutb, const float* __restrict__ bout,
                            float* __restrict__ outy, float* __restrict__ hout,
                            float* __restrict__ cout) {
  __shared__ __align__(16) short acts_s[16 * 512];  // [row][k] swizzled, dbuf e,h
  __shared__ __align__(16) float xs[16 * 128];      // [row][t*2+{0,1}]

  const int tid  = threadIdx.x;
  const int lane = tid & 63;
  const int w    = tid >> 6;        // wave 0..7 -> col slice w*16 of each gate
  const int row0 = blockIdx.x * 16;
  const int cl   = lane & 15;       // A-frag row / C-tile col
  const int lq   = lane >> 4;       // lane quad
  const int er   = tid >> 4;        // e-writer row (tid<256: 0..15)
  const int cg   = tid & 15;        // e-writer col granule

  // preload x for this block's 16 rows (2048 floats = 512 float4)
  {
    const float4* src = (const float4*)(x + (size_t)row0 * 128);
    ((float4*)xs)[tid] = src[tid];
  }

  float bgs[4];
  #pragma unroll
  for (int g = 0; g < 4; g++) bgs[g] = bc[g * 128 + w * 16 + cl];
  const float bov = (cl < 5) ? bout[cl] : 0.f;

  // gate weights resident in registers: 32 fragments = 128 regs
  bf16x8 wreg[8][4];
  {
    const bf16x8* wptr = (const bf16x8*)Wcb;
    #pragma unroll
    for (int kt = 0; kt < 8; kt++)
      #pragma unroll
      for (int g = 0; g < 4; g++)
        wreg[kt][g] = wptr[(size_t)(kt * 32 + g * 8 + w) * 64 + lane];
  }
  bf16x8 wof[4];
  if (w == 0) {
    #pragma unroll
    for (int kyt = 0; kyt < 4; kyt++)
      wof[kyt] = *(const bf16x8*)(Woutb + (size_t)(kyt * 64 + lane) * 8);
  }

  __syncthreads();  // xs ready

  // init: e(0) -> e-buf 0; h(-1)=0 -> h-buf 1; e-table prefetch regs
  float4 ta0a, ta0b, ta1a, ta1b, tcta, tctb;
  if (tid < 256) {
    ta0a = *(const float4*)(A0 + cg*8);   ta0b = *(const float4*)(A0 + cg*8 + 4);
    ta1a = *(const float4*)(A1 + cg*8);   ta1b = *(const float4*)(A1 + cg*8 + 4);
    tcta = *(const float4*)(Ctab + cg*8); tctb = *(const float4*)(Ctab + cg*8 + 4);
    float x0 = xs[er * 128], x1 = xs[er * 128 + 1];
    bf16x8 v;
    v[0] = f2bf_s(fmaxf(fmaf(ta0a.x, x0, fmaf(ta1a.x, x1, tcta.x)), 0.f));
    v[1] = f2bf_s(fmaxf(fmaf(ta0a.y, x0, fmaf(ta1a.y, x1, tcta.y)), 0.f));
    v[2] = f2bf_s(fmaxf(fmaf(ta0a.z, x0, fmaf(ta1a.z, x1, tcta.z)), 0.f));
    v[3] = f2bf_s(fmaxf(fmaf(ta0a.w, x0, fmaf(ta1a.w, x1, tcta.w)), 0.f));
    v[4] = f2bf_s(fmaxf(fmaf(ta0b.x, x0, fmaf(ta1b.x, x1, tctb.x)), 0.f));
    v[5] = f2bf_s(fmaxf(fmaf(ta0b.y, x0, fmaf(ta1b.y, x1, tctb.y)), 0.f));
    v[6] = f2bf_s(fmaxf(fmaf(ta0b.z, x0, fmaf(ta1b.z, x1, tctb.z)), 0.f));
    v[7] = f2bf_s(fmaxf(fmaf(ta0b.w, x0, fmaf(ta1b.w, x1, tctb.w)), 0.f));
    *(bf16x8*)&acts_s[er * 512 + ((cg ^ (er & 7)) << 3)] = v;            // e-buf 0
    bf16x8 z = (bf16x8)0;
    *(bf16x8*)&acts_s[er * 512 + (((48 + cg) ^ (er & 7)) << 3)] = z;     // h-buf 1
  }

  f32x4 cstate = {0.f, 0.f, 0.f, 0.f};
  float hl[4];

  #pragma unroll 1
  for (int t = 0; t < TT; t++) {
    __syncthreads();                 // step t-1 writes visible; t-1 reads done
    const int ebuf = t & 1;          // e(t)
    const int hbuf = (t + 1) & 1;    // h(t-1)

    // prefetch e-tables for t+1 (latency hides under MFMA phase)
    if (t < TT - 1 && tid < 256) {
      const float* a0p = A0 + (t + 1) * 128 + cg * 8;
      const float* a1p = A1 + (t + 1) * 128 + cg * 8;
      const float* ccp = Ctab + (t + 1) * 128 + cg * 8;
      ta0a = *(const float4*)a0p;       ta0b = *(const float4*)(a0p + 4);
      ta1a = *(const float4*)a1p;       ta1b = *(const float4*)(a1p + 4);
      tcta = *(const float4*)ccp;       tctb = *(const float4*)(ccp + 4);
    }

    // y(t-1) = h(t-1) @ Wout^T + bout  (wave 0)
    if (w == 0 && t > 0) {
      f32x4 ya = (f32x4){0.f, 0.f, 0.f, 0.f};
      #pragma unroll
      for (int kyt = 0; kyt < 4; kyt++) {
        int k = 256 + hbuf * 128 + (kyt * 4 + lq) * 8;
        bf16x8 ah = *(const bf16x8*)&acts_s[aidx(cl, k)];
        ya = __builtin_amdgcn_mfma_f32_16x16x32_bf16(ah, wof[kyt], ya, 0, 0, 0);
      }
      if (cl < 5) {
        #pragma unroll
        for (int q = 0; q < 4; q++) {
          int brow = row0 + lq * 4 + q;
          outy[((size_t)brow * TT + (t - 1)) * 5 + cl] = ya[q] + bov;
        }
      }
    }

    // gates = [e(t) | h(t-1)] @ Wc  (B-fragments from registers)
    f32x4 acc[4];
    #pragma unroll
    for (int g = 0; g < 4; g++) acc[g] = (f32x4){bgs[g], bgs[g], bgs[g], bgs[g]};

    #pragma unroll
    for (int kt = 0; kt < 8; kt++) {
      int gk = (kt < 4) ? (ebuf * 16 + kt * 4 + lq)
                        : (32 + hbuf * 16 + (kt - 4) * 4 + lq);
      bf16x8 a0 = *(const bf16x8*)&acts_s[cl * 512 + ((gk ^ (cl & 7)) << 3)];
      #pragma unroll
      for (int g = 0; g < 4; g++)
        acc[g] = __builtin_amdgcn_mfma_f32_16x16x32_bf16(a0, wreg[kt][g], acc[g], 0, 0, 0);
    }

    // elementwise LSTM update (lane-local), h(t) -> h-buf t&1
    #pragma unroll
    for (int q = 0; q < 4; q++) {
      float Ei = exp2g(acc[0][q]);            // e^{-i}
      float Ef = exp2g(acc[1][q]);            // e^{-f}
      float Eg = exp2g(acc[2][q]);            // e^{2g}
      float Eo = exp2g(acc[3][q]);            // e^{-o}
      float di = 1.f + Ei, dg = 1.f + Eg;
      float ig = (Eg - 1.f) * rcpg(di * dg);  // sig(i)*tanh(g)
      float fv = rcpg(1.f + Ef);              // sig(f)
      float cn = fmaf(fv, cstate[q], ig);
      cstate[q] = cn;
      float Ec = exp2g(cn * (2.f * L2E));     // e^{2c}
      float hn = (Ec - 1.f) * rcpg((1.f + Eo) * (1.f + Ec));
      hl[q] = hn;
      int row = lq * 4 + q;
      int k   = 256 + (t & 1) * 128 + w * 16 + cl;
      acts_s[aidx(row, k)] = f2bf_s(hn);
    }

    // e(t+1) -> e-buf (t+1)&1 (tables already in regs)
    if (t < TT - 1 && tid < 256) {
      float x0 = xs[er * 128 + (t + 1) * 2], x1 = xs[er * 128 + (t + 1) * 2 + 1];
      bf16x8 v;
      v[0] = f2bf_s(fmaxf(fmaf(ta0a.x, x0, fmaf(ta1a.x, x1, tcta.x)), 0.f));
      v[1] = f2bf_s(fmaxf(fmaf(ta0a.y, x0, fmaf(ta1a.y, x1, tcta.y)), 0.f));
      v[2] = f2bf_s(fmaxf(fmaf(ta0a.z, x0, fmaf(ta1a.z, x1, tcta.z)), 0.f));
      v[3] = f2bf_s(fmaxf(fmaf(ta0a.w, x0, fmaf(ta1a.w, x1, tcta.w)), 0.f));
      v[4] = f2bf_s(fmaxf(fmaf(ta0b.x, x0, fmaf(ta1b.x, x1, tctb.x)), 0.f));
      v[5] = f2bf_s(fmaxf(fmaf(ta0b.y, x0, fmaf(ta1b.y, x1, tctb.y)), 0.f));
      v[6] = f2bf_s(fmaxf(fmaf(ta0b.z, x0, fmaf(ta1b.z, x1, tctb.z)), 0.f));
      v[7] = f2bf_s(fmaxf(fmaf(ta0b.w, x0, fmaf(ta1b.w, x1, tctb.w)), 0.f));
      int gk = ((t + 1) & 1) * 16 + cg;
      *(bf16x8*)&acts_s[er * 512 + ((gk ^ (er & 7)) << 3)] = v;
    }
  }

  __syncthreads();                   // h(TT-1) visible
  if (w == 0) {                      // final y(TT-1)
    f32x4 ya = (f32x4){0.f, 0.f, 0.f, 0.f};
    #pragma unroll
    for (int kyt = 0; kyt < 4; kyt++) {
      int k = 256 + ((TT - 1) & 1) * 128 + (kyt * 4 + lq) * 8;
      bf16x8 ah = *(const bf16x8*)&acts_s[aidx(cl, k)];
      ya = __builtin_amdgcn_mfma_f32_16x16x32_bf16(ah, wof[kyt], ya, 0, 0, 0);
    }
    if (cl < 5) {
      #pragma unroll
      for (int q = 0; q < 4; q++) {
        int brow = row0 + lq * 4 + q;
        outy[((size_t)brow * TT + (TT - 1)) * 5 + cl] = ya[q] + bov;
      }
    }
  }

  // final h, c
  #pragma unroll
  for (int q = 0; q < 4; q++) {
    int brow = row0 + lq * 4 + q;
    int col  = w * 16 + cl;
    hout[(size_t)brow * 128 + col] = hl[q];
    cout[(size_t)brow * 128 + col] = cstate[q];
  }
}

// ---- 5. per-(t,k) output BN partial stats (256 blocks = full chip) ----
__global__ void ostats_kernel(const float* __restrict__ outy, float* __restrict__ ostp) {
  int t = blockIdx.x >> 2, part = blockIdx.x & 3;
  int tid = threadIdx.x;
  float s[5] = {0,0,0,0,0}, s2[5] = {0,0,0,0,0};
  int b0 = part * 2048;
  for (int b = b0 + tid; b < b0 + 2048; b += 256) {
    const float* p = outy + ((size_t)b * TT + t) * 5;
    #pragma unroll
    for (int k = 0; k < 5; k++) { float v = p[k]; s[k] += v; s2[k] += v*v; }
  }
  __shared__ float red[4][10];
  int lane = tid & 63, w = tid >> 6;
  #pragma unroll
  for (int off = 32; off > 0; off >>= 1) {
    #pragma unroll
    for (int k = 0; k < 5; k++) {
      s[k]  += __shfl_down(s[k], off);
      s2[k] += __shfl_down(s2[k], off);
    }
  }
  if (lane == 0) {
    #pragma unroll
    for (int k = 0; k < 5; k++) { red[w][k] = s[k]; red[w][5+k] = s2[k]; }
  }
  __syncthreads();
  if (tid < 10) ostp[blockIdx.x * 10 + tid] = red[0][tid]+red[1][tid]+red[2][tid]+red[3][tid];
}

// ---- 5b. finalize: per-(t,k) scale/shift ----
__global__ void ofin_kernel(const float* __restrict__ ostp,
                            const float* __restrict__ og, const float* __restrict__ ob,
                            float* __restrict__ sc, float* __restrict__ sh) {
  int i = threadIdx.x;               // 320
  if (i >= 320) return;
  int t = i / 5, k = i - t * 5;
  const float invB = 1.f / (float)BB;
  float m  = (ostp[(t*4+0)*10+k]   + ostp[(t*4+1)*10+k]   + ostp[(t*4+2)*10+k]   + ostp[(t*4+3)*10+k]) * invB;
  float s2 = (ostp[(t*4+0)*10+5+k] + ostp[(t*4+1)*10+5+k] + ostp[(t*4+2)*10+5+k] + ostp[(t*4+3)*10+5+k]) * invB;
  float v = s2 - m * m;
  float scale = rsqrtf(v + 1e-5f) * og[k];
  sc[i] = scale;
  sh[i] = ob[k] - m * scale;
}

// ---- 6. normalize outs in place: out = y*sc[i%320] + sh[i%320] ----
__global__ void onorm_kernel(float* __restrict__ outy, const float* __restrict__ sc,
                             const float* __restrict__ sh) {
  const int N = BB * TT * 5;
  for (int i = blockIdx.x * 256 + threadIdx.x; i < N; i += gridDim.x * 256) {
    int j = i % 320;
    outy[i] = fmaf(outy[i], sc[j], sh[j]);
  }
}

extern "C" void kernel_launch(void* const* d_in, const int* in_sizes, int n_in,
                              void* d_out, int out_size, void* d_ws, size_t ws_size,
                              hipStream_t stream) {
  const float* xin  = (const float*)d_in[0];
  const float* ing  = (const float*)d_in[1];
  const float* inb  = (const float*)d_in[2];
  const float* Wemb = (const float*)d_in[3];
  const float* bemb = (const float*)d_in[4];
  const float* eg   = (const float*)d_in[5];
  const float* eb   = (const float*)d_in[6];
  const float* Wih  = (const float*)d_in[7];
  const float* Whh  = (const float*)d_in[8];
  const float* bih  = (const float*)d_in[9];
  const float* bhh  = (const float*)d_in[10];
  const float* Wout = (const float*)d_in[11];
  const float* bout = (const float*)d_in[12];
  const float* og   = (const float*)d_in[13];
  const float* ob   = (const float*)d_in[14];

  float* ws    = (float*)d_ws;
  float* stats = ws;             // 320
  float* A0    = ws + 1024;      // 8192
  float* A1    = ws + 9216;      // 8192
  float* Ct    = ws + 17408;     // 8192
  float* bc    = ws + 25600;     // 512
  short* Wcb   = (short*)(ws + 26624);   // 131072 shorts (256 KB)
  short* Woutb = (short*)(ws + 92160);   // 2048 shorts (4 KB)
  float* ostp  = ws + 93184;     // 2560
  float* sc    = ws + 95744;     // 320
  float* sh    = ws + 96064;     // 320

  float* outy = (float*)d_out;
  float* hout = outy + (size_t)BB * TT * 5;
  float* cout = hout + (size_t)BB * 128;

  prep_kernel <<<67, 256, 0, stream>>>(Wih, Whh, bih, bhh, Wout, Wcb, Woutb, bc);
  stats_kernel<<<64, 256, 0, stream>>>(xin, stats);
  coef_kernel <<<1, 128, 0, stream>>>(stats, Wemb, bemb, ing, inb, eg, eb, A0, A1, Ct);
  lstm_kernel <<<512, 512, 0, stream>>>(xin, A0, A1, Ct, Wcb, bc, Woutb, bout,
                                        outy, hout, cout);
  ostats_kernel<<<256, 256, 0, stream>>>(outy, ostp);
  ofin_kernel <<<1, 320, 0, stream>>>(ostp, og, ob, sc, sh);
  onorm_kernel<<<2048, 256, 0, stream>>>(outy, sc, sh);
}

// Round 6
// 744.740 us; speedup vs baseline: 1.3690x; 1.3690x over previous
//
#include <hip/hip_runtime.h>
#include <hip/hip_bf16.h>

#define BB 8192
#define TT 64
#define L2E 1.44269504088896f
#define AROW 384                    // acts row stride (shorts): e[0,128) h0[128,256) h1[256,384)
#define PPAD 516                    // partial row stride (f32); 4*PPAD % 32 == 16 -> lq groups offset
#define PBUFF (32 * PPAD)
#define LSTM_LDS_BYTES (32 * AROW * 2 + 2 * PBUFF * 4)   // 24576 + 132096 = 156672

typedef __attribute__((ext_vector_type(8))) short bf16x8;
typedef __attribute__((ext_vector_type(4))) float f32x4;

__device__ __forceinline__ float exp2g(float x) { return __builtin_amdgcn_exp2f(x); }
__device__ __forceinline__ float rcpg(float x)  { return __builtin_amdgcn_rcpf(x); }
__device__ __forceinline__ short f2bf_s(float x) {
  __hip_bfloat16 b = __float2bfloat16(x);
  return *reinterpret_cast<short*>(&b);
}
__device__ __forceinline__ float bf2f(short v) {
  unsigned u = ((unsigned)(unsigned short)v) << 16;
  return __uint_as_float(u);
}
__device__ __forceinline__ bf16x8 ldfrag(const short* acts, int row, int kg) {
  return *(const bf16x8*)&acts[row * AROW + ((kg ^ (row & 7)) << 3)];
}

// ---- 1. weights -> bf16 MFMA-fragment order, exp2-prescaled; bc = (b_ih+b_hh)*scale ----
__global__ void prep_kernel(const float* __restrict__ Wih, const float* __restrict__ Whh,
                            const float* __restrict__ bih, const float* __restrict__ bhh,
                            const float* __restrict__ Wout,
                            short* __restrict__ Wcb, short* __restrict__ Woutb,
                            float* __restrict__ bc) {
  int idx = blockIdx.x * 256 + threadIdx.x;   // 17152 total
  if (idx < 16384) {
    int l = idx & 63, f = idx >> 6;
    int kt = f >> 5, nt = f & 31;
    int k0 = kt * 32 + ((l >> 4) << 3);
    int col = nt * 16 + (l & 15);
    int gate = col >> 7;
    float s = (gate == 2) ? (2.f * L2E) : (-L2E);
    const float* src = (k0 < 128) ? (Wih + col * 128 + k0) : (Whh + col * 128 + (k0 - 128));
    bf16x8 v;
    #pragma unroll
    for (int e = 0; e < 8; e++) v[e] = f2bf_s(src[e] * s);
    *(bf16x8*)(Wcb + (size_t)idx * 8) = v;
  } else if (idx < 16640) {
    int i2 = idx - 16384;
    int l = i2 & 63, f = i2 >> 6;              // f = kyt
    int k0 = f * 32 + ((l >> 4) << 3);
    int col = l & 15;
    bf16x8 v;
    #pragma unroll
    for (int e = 0; e < 8; e++)
      v[e] = (col < 5) ? f2bf_s(Wout[col * 128 + k0 + e]) : (short)0;
    *(bf16x8*)(Woutb + (size_t)i2 * 8) = v;
  } else {
    int i3 = idx - 16640;
    int gate = i3 >> 7;
    float s = (gate == 2) ? (2.f * L2E) : (-L2E);
    bc[i3] = (bih[i3] + bhh[i3]) * s;
  }
}

// ---- 2. per-t raw input moments over batch ----
__global__ void stats_kernel(const float* __restrict__ x, float* __restrict__ stats) {
  int t = blockIdx.x, tid = threadIdx.x;
  float s0=0, s1=0, s2=0, s3=0, s4=0;
  for (int b = tid; b < BB; b += 256) {
    const float* p = x + ((size_t)b * TT + t) * 2;
    float x0 = p[0], x1 = p[1];
    s0 += x0; s1 += x1; s2 += x0*x0; s3 += x0*x1; s4 += x1*x1;
  }
  __shared__ float red[4][5];
  int lane = tid & 63, w = tid >> 6;
  #pragma unroll
  for (int off = 32; off > 0; off >>= 1) {
    s0 += __shfl_down(s0, off); s1 += __shfl_down(s1, off);
    s2 += __shfl_down(s2, off); s3 += __shfl_down(s3, off); s4 += __shfl_down(s4, off);
  }
  if (lane == 0) { red[w][0]=s0; red[w][1]=s1; red[w][2]=s2; red[w][3]=s3; red[w][4]=s4; }
  __syncthreads();
  if (tid < 5) stats[t*5 + tid] = red[0][tid] + red[1][tid] + red[2][tid] + red[3][tid];
}

// ---- 3. fold input-BN + embed Linear + per-step embed-BN into A0/A1/C ----
__global__ void coef_kernel(const float* __restrict__ stats,
                            const float* __restrict__ Wemb, const float* __restrict__ bemb,
                            const float* __restrict__ ing, const float* __restrict__ inb,
                            const float* __restrict__ eg, const float* __restrict__ eb,
                            float* __restrict__ A0, float* __restrict__ A1, float* __restrict__ Ct) {
  __shared__ float st[64][5];
  __shared__ float glob[4];
  int tid = threadIdx.x;  // 128
  for (int i = tid; i < 320; i += 128) st[i / 5][i % 5] = stats[i];
  __syncthreads();
  if (tid == 0) {
    float S0=0, S1=0, S00=0, S11=0;
    for (int t = 0; t < 64; t++) { S0+=st[t][0]; S1+=st[t][1]; S00+=st[t][2]; S11+=st[t][4]; }
    float inv_n = 1.f / (float)(BB * TT);
    float M0 = S0*inv_n, M1 = S1*inv_n;
    float V0 = S00*inv_n - M0*M0, V1 = S11*inv_n - M1*M1;
    float P0 = rsqrtf(V0 + 1e-5f) * ing[0];
    float P1 = rsqrtf(V1 + 1e-5f) * ing[1];
    glob[0]=P0; glob[1]=P1; glob[2]=inb[0]-M0*P0; glob[3]=inb[1]-M1*P1;
  }
  __syncthreads();
  float P0=glob[0], P1=glob[1], Q0=glob[2], Q1=glob[3];
  int j = tid;
  float w0 = Wemb[j*2], w1 = Wemb[j*2+1];
  float a0 = P0*w0, a1 = P1*w1;
  float cj = Q0*w0 + Q1*w1 + bemb[j];
  float gam = eg[j], bet = eb[j];
  float invB = 1.f / (float)BB;
  for (int t = 0; t < 64; t++) {
    float m0 = st[t][0]*invB, m1 = st[t][1]*invB;
    float v00 = st[t][2]*invB - m0*m0;
    float v01 = st[t][3]*invB - m0*m1;
    float v11 = st[t][4]*invB - m1*m1;
    float mean = a0*m0 + a1*m1 + cj;
    float var  = a0*a0*v00 + 2.f*a0*a1*v01 + a1*a1*v11;
    float G = rsqrtf(var + 1e-5f) * gam;
    A0[t*128 + j] = G * a0;
    A1[t*128 + j] = G * a1;
    Ct[t*128 + j] = G * cj + (bet - mean * G);
  }
}

// write e(t) for row er, granule cg (tables from L2, x from global)
__device__ __forceinline__ void write_e(short* acts,
                                        const float* __restrict__ A0, const float* __restrict__ A1,
                                        const float* __restrict__ Ct,
                                        int t, int er, int cg,
                                        const float* __restrict__ x, int row0) {
  const float* a0p = A0 + t*128 + cg*8;
  const float* a1p = A1 + t*128 + cg*8;
  const float* ccp = Ct + t*128 + cg*8;
  const float4 a0a = *(const float4*)a0p, a0b = *(const float4*)(a0p + 4);
  const float4 a1a = *(const float4*)a1p, a1b = *(const float4*)(a1p + 4);
  const float4 cta = *(const float4*)ccp, ctb = *(const float4*)(ccp + 4);
  const float* xp = x + ((size_t)(row0 + er) * TT + t) * 2;
  float x0 = xp[0], x1 = xp[1];
  bf16x8 v;
  v[0] = f2bf_s(fmaxf(fmaf(a0a.x, x0, fmaf(a1a.x, x1, cta.x)), 0.f));
  v[1] = f2bf_s(fmaxf(fmaf(a0a.y, x0, fmaf(a1a.y, x1, cta.y)), 0.f));
  v[2] = f2bf_s(fmaxf(fmaf(a0a.z, x0, fmaf(a1a.z, x1, cta.z)), 0.f));
  v[3] = f2bf_s(fmaxf(fmaf(a0a.w, x0, fmaf(a1a.w, x1, cta.w)), 0.f));
  v[4] = f2bf_s(fmaxf(fmaf(a0b.x, x0, fmaf(a1b.x, x1, ctb.x)), 0.f));
  v[5] = f2bf_s(fmaxf(fmaf(a0b.y, x0, fmaf(a1b.y, x1, ctb.y)), 0.f));
  v[6] = f2bf_s(fmaxf(fmaf(a0b.z, x0, fmaf(a1b.z, x1, ctb.z)), 0.f));
  v[7] = f2bf_s(fmaxf(fmaf(a0b.w, x0, fmaf(a1b.w, x1, ctb.w)), 0.f));
  *(bf16x8*)&acts[er * AROW + ((cg ^ (er & 7)) << 3)] = v;
}

// ---- 4. split-K MFMA recurrence: 256 blocks x 32 rows, 16 waves (8 e-part + 8 h-part) ----
__launch_bounds__(1024, 4)
__global__ void lstm_kernel(const float* __restrict__ x,
                            const float* __restrict__ A0, const float* __restrict__ A1,
                            const float* __restrict__ Ctab,
                            const short* __restrict__ Wcb, const float* __restrict__ bc,
                            const short* __restrict__ Woutb, const float* __restrict__ bout,
                            float* __restrict__ outy, float* __restrict__ hout,
                            float* __restrict__ cout) {
  extern __shared__ __align__(16) char smraw[];
  short* acts = (short*)smraw;                       // [32][AROW]
  float* part = (float*)(smraw + 32 * AROW * 2);     // [2][32][PPAD]

  const int tid  = threadIdx.x;
  const int lane = tid & 63;
  const int w    = tid >> 6;        // 0..15
  const int s    = w & 7;           // col slice
  const int half = w >> 3;          // 0: e-part + write_e + y; 1: h-part + elementwise
  const int cl   = lane & 15;
  const int lq   = lane >> 4;
  const int er   = (tid >> 4) & 31; // e-writer row
  const int cg   = tid & 15;        // e-writer granule
  const int row0 = blockIdx.x * 32;

  // 16 weight fragments (64 VGPR): this half's K-range
  bf16x8 wreg[4][4];
  {
    const bf16x8* wptr = (const bf16x8*)Wcb;
    #pragma unroll
    for (int kti = 0; kti < 4; kti++)
      #pragma unroll
      for (int g = 0; g < 4; g++)
        wreg[kti][g] = wptr[(size_t)((half * 4 + kti) * 32 + g * 8 + s) * 64 + lane];
  }

  float bgs[4] = {0.f, 0.f, 0.f, 0.f};
  if (half) {
    #pragma unroll
    for (int g = 0; g < 4; g++) bgs[g] = bc[g * 128 + s * 16 + cl];
  }
  const float bov = (cl < 5) ? bout[cl] : 0.f;

  // prologue: e(0) by half-0; h(-1)=0 -> hbuf1 by half-1
  if (!half) {
    write_e(acts, A0, A1, Ctab, 0, er, cg, x, row0);
  } else {
    bf16x8 z = (bf16x8)0;
    int kg = 32 + cg;
    *(bf16x8*)&acts[er * AROW + ((kg ^ (er & 7)) << 3)] = z;
  }
  __syncthreads();
  // epart(0) -> part[0]
  if (!half) {
    #pragma unroll
    for (int mt = 0; mt < 2; mt++) {
      f32x4 ae[4] = {{0,0,0,0},{0,0,0,0},{0,0,0,0},{0,0,0,0}};
      #pragma unroll
      for (int kti = 0; kti < 4; kti++) {
        bf16x8 a = ldfrag(acts, mt * 16 + cl, kti * 4 + lq);
        #pragma unroll
        for (int g = 0; g < 4; g++)
          ae[g] = __builtin_amdgcn_mfma_f32_16x16x32_bf16(a, wreg[kti][g], ae[g], 0, 0, 0);
      }
      #pragma unroll
      for (int q = 0; q < 4; q++) {
        float4 v; v.x = ae[0][q]; v.y = ae[1][q]; v.z = ae[2][q]; v.w = ae[3][q];
        *(float4*)&part[(mt * 16 + lq * 4 + q) * PPAD + (s * 16 + cl) * 4] = v;
      }
    }
  }
  __syncthreads();

  f32x4 acc[4][2];
  f32x4 cst[2] = {{0,0,0,0},{0,0,0,0}};

  #pragma unroll 1
  for (int t = 0; t < TT; t++) {
    const int hb_prev = (t + 1) & 1;   // h(t-1) buffer
    const int hb_cur  = t & 1;         // h(t) buffer

    // ---- P1 ----
    if (half) {
      // h-part MFMA(t)
      #pragma unroll
      for (int g = 0; g < 4; g++) {
        acc[g][0] = (f32x4){bgs[g], bgs[g], bgs[g], bgs[g]};
        acc[g][1] = acc[g][0];
      }
      #pragma unroll
      for (int kti = 0; kti < 4; kti++) {
        int kg = 16 + hb_prev * 16 + kti * 4 + lq;
        bf16x8 a0 = ldfrag(acts, cl, kg);
        bf16x8 a1 = ldfrag(acts, 16 + cl, kg);
        #pragma unroll
        for (int g = 0; g < 4; g++) {
          acc[g][0] = __builtin_amdgcn_mfma_f32_16x16x32_bf16(a0, wreg[kti][g], acc[g][0], 0, 0, 0);
          acc[g][1] = __builtin_amdgcn_mfma_f32_16x16x32_bf16(a1, wreg[kti][g], acc[g][1], 0, 0, 0);
        }
      }
    } else {
      if (t < TT - 1) write_e(acts, A0, A1, Ctab, t + 1, er, cg, x, row0);
      if (w < 2 && t > 0) {            // y(t-1), waves 0-1
        f32x4 ya = (f32x4){0, 0, 0, 0};
        #pragma unroll
        for (int kyt = 0; kyt < 4; kyt++) {
          bf16x8 wo = *(const bf16x8*)(Woutb + (size_t)(kyt * 64 + lane) * 8);
          bf16x8 ah = ldfrag(acts, w * 16 + cl, 16 + hb_prev * 16 + kyt * 4 + lq);
          ya = __builtin_amdgcn_mfma_f32_16x16x32_bf16(ah, wo, ya, 0, 0, 0);
        }
        if (cl < 5) {
          #pragma unroll
          for (int q = 0; q < 4; q++)
            outy[((size_t)(row0 + w * 16 + lq * 4 + q) * TT + (t - 1)) * 5 + cl] = ya[q] + bov;
        }
      }
    }
    __syncthreads();

    // ---- P2 ----
    if (!half) {
      if (t < TT - 1) {                // e-part MFMA(t+1) -> part[(t+1)&1]
        float* pdst = part + hb_prev * PBUFF;
        #pragma unroll
        for (int mt = 0; mt < 2; mt++) {
          f32x4 ae[4] = {{0,0,0,0},{0,0,0,0},{0,0,0,0},{0,0,0,0}};
          #pragma unroll
          for (int kti = 0; kti < 4; kti++) {
            bf16x8 a = ldfrag(acts, mt * 16 + cl, kti * 4 + lq);
            #pragma unroll
            for (int g = 0; g < 4; g++)
              ae[g] = __builtin_amdgcn_mfma_f32_16x16x32_bf16(a, wreg[kti][g], ae[g], 0, 0, 0);
          }
          #pragma unroll
          for (int q = 0; q < 4; q++) {
            float4 v; v.x = ae[0][q]; v.y = ae[1][q]; v.z = ae[2][q]; v.w = ae[3][q];
            *(float4*)&pdst[(mt * 16 + lq * 4 + q) * PPAD + (s * 16 + cl) * 4] = v;
          }
        }
      }
    } else {
      // combine + elementwise -> h(t)
      const float* psrc = part + hb_cur * PBUFF;
      const int j = s * 16 + cl;
      #pragma unroll
      for (int mt = 0; mt < 2; mt++) {
        #pragma unroll
        for (int q = 0; q < 4; q++) {
          int row = mt * 16 + lq * 4 + q;
          float4 p = *(const float4*)&psrc[row * PPAD + j * 4];
          float Ei = exp2g(acc[0][mt][q] + p.x);          // e^{-i}
          float Ef = exp2g(acc[1][mt][q] + p.y);          // e^{-f}
          float Eg = exp2g(acc[2][mt][q] + p.z);          // e^{2g}
          float Eo = exp2g(acc[3][mt][q] + p.w);          // e^{-o}
          float di = 1.f + Ei, dg = 1.f + Eg;
          float ig = (Eg - 1.f) * rcpg(di * dg);          // sig(i)*tanh(g)
          float fv = rcpg(1.f + Ef);                      // sig(f)
          float cn = fmaf(fv, cst[mt][q], ig);
          cst[mt][q] = cn;
          float Ec = exp2g(cn * (2.f * L2E));             // e^{2c}
          float hn = (Ec - 1.f) * rcpg((1.f + Eo) * (1.f + Ec));
          int kg2 = 16 + hb_cur * 16 + (j >> 3);
          acts[row * AROW + ((kg2 ^ (row & 7)) << 3) + (j & 7)] = f2bf_s(hn);
        }
      }
    }
    __syncthreads();
  }

  // epilogue: y(63); final h, c
  if (w < 2) {
    const int hb = (TT - 1) & 1;
    f32x4 ya = (f32x4){0, 0, 0, 0};
    #pragma unroll
    for (int kyt = 0; kyt < 4; kyt++) {
      bf16x8 wo = *(const bf16x8*)(Woutb + (size_t)(kyt * 64 + lane) * 8);
      bf16x8 ah = ldfrag(acts, w * 16 + cl, 16 + hb * 16 + kyt * 4 + lq);
      ya = __builtin_amdgcn_mfma_f32_16x16x32_bf16(ah, wo, ya, 0, 0, 0);
    }
    if (cl < 5) {
      #pragma unroll
      for (int q = 0; q < 4; q++)
        outy[((size_t)(row0 + w * 16 + lq * 4 + q) * TT + (TT - 1)) * 5 + cl] = ya[q] + bov;
    }
  }
  if (half) {
    const int hb = (TT - 1) & 1;
    const int j = s * 16 + cl;
    #pragma unroll
    for (int mt = 0; mt < 2; mt++) {
      #pragma unroll
      for (int q = 0; q < 4; q++) {
        int row = mt * 16 + lq * 4 + q;
        int kg2 = 16 + hb * 16 + (j >> 3);
        float hv = bf2f(acts[row * AROW + ((kg2 ^ (row & 7)) << 3) + (j & 7)]);
        hout[(size_t)(row0 + row) * 128 + j] = hv;
        cout[(size_t)(row0 + row) * 128 + j] = cst[mt][q];
      }
    }
  }
}

// ---- 5. per-(t,k) output BN partial stats (256 blocks = full chip) ----
__global__ void ostats_kernel(const float* __restrict__ outy, float* __restrict__ ostp) {
  int t = blockIdx.x >> 2, part = blockIdx.x & 3;
  int tid = threadIdx.x;
  float s[5] = {0,0,0,0,0}, s2[5] = {0,0,0,0,0};
  int b0 = part * 2048;
  for (int b = b0 + tid; b < b0 + 2048; b += 256) {
    const float* p = outy + ((size_t)b * TT + t) * 5;
    #pragma unroll
    for (int k = 0; k < 5; k++) { float v = p[k]; s[k] += v; s2[k] += v*v; }
  }
  __shared__ float red[4][10];
  int lane = tid & 63, w = tid >> 6;
  #pragma unroll
  for (int off = 32; off > 0; off >>= 1) {
    #pragma unroll
    for (int k = 0; k < 5; k++) {
      s[k]  += __shfl_down(s[k], off);
      s2[k] += __shfl_down(s2[k], off);
    }
  }
  if (lane == 0) {
    #pragma unroll
    for (int k = 0; k < 5; k++) { red[w][k] = s[k]; red[w][5+k] = s2[k]; }
  }
  __syncthreads();
  if (tid < 10) ostp[blockIdx.x * 10 + tid] = red[0][tid]+red[1][tid]+red[2][tid]+red[3][tid];
}

// ---- 5b. finalize: per-(t,k) scale/shift ----
__global__ void ofin_kernel(const float* __restrict__ ostp,
                            const float* __restrict__ og, const float* __restrict__ ob,
                            float* __restrict__ sc, float* __restrict__ sh) {
  int i = threadIdx.x;               // 320
  if (i >= 320) return;
  int t = i / 5, k = i - t * 5;
  const float invB = 1.f / (float)BB;
  float m  = (ostp[(t*4+0)*10+k]   + ostp[(t*4+1)*10+k]   + ostp[(t*4+2)*10+k]   + ostp[(t*4+3)*10+k]) * invB;
  float s2 = (ostp[(t*4+0)*10+5+k] + ostp[(t*4+1)*10+5+k] + ostp[(t*4+2)*10+5+k] + ostp[(t*4+3)*10+5+k]) * invB;
  float v = s2 - m * m;
  float scale = rsqrtf(v + 1e-5f) * og[k];
  sc[i] = scale;
  sh[i] = ob[k] - m * scale;
}

// ---- 6. normalize outs in place ----
__global__ void onorm_kernel(float* __restrict__ outy, const float* __restrict__ sc,
                             const float* __restrict__ sh) {
  const int N = BB * TT * 5;
  for (int i = blockIdx.x * 256 + threadIdx.x; i < N; i += gridDim.x * 256) {
    int j = i % 320;
    outy[i] = fmaf(outy[i], sc[j], sh[j]);
  }
}

extern "C" void kernel_launch(void* const* d_in, const int* in_sizes, int n_in,
                              void* d_out, int out_size, void* d_ws, size_t ws_size,
                              hipStream_t stream) {
  const float* xin  = (const float*)d_in[0];
  const float* ing  = (const float*)d_in[1];
  const float* inb  = (const float*)d_in[2];
  const float* Wemb = (const float*)d_in[3];
  const float* bemb = (const float*)d_in[4];
  const float* eg   = (const float*)d_in[5];
  const float* eb   = (const float*)d_in[6];
  const float* Wih  = (const float*)d_in[7];
  const float* Whh  = (const float*)d_in[8];
  const float* bih  = (const float*)d_in[9];
  const float* bhh  = (const float*)d_in[10];
  const float* Wout = (const float*)d_in[11];
  const float* bout = (const float*)d_in[12];
  const float* og   = (const float*)d_in[13];
  const float* ob   = (const float*)d_in[14];

  float* ws    = (float*)d_ws;
  float* stats = ws;             // 320
  float* A0    = ws + 1024;      // 8192
  float* A1    = ws + 9216;      // 8192
  float* Ct    = ws + 17408;     // 8192
  float* bc    = ws + 25600;     // 512
  short* Wcb   = (short*)(ws + 26624);   // 131072 shorts (256 KB)
  short* Woutb = (short*)(ws + 92160);   // 2048 shorts (4 KB)
  float* ostp  = ws + 93184;     // 2560
  float* sc    = ws + 95744;     // 320
  float* sh    = ws + 96064;     // 320

  float* outy = (float*)d_out;
  float* hout = outy + (size_t)BB * TT * 5;
  float* cout = hout + (size_t)BB * 128;

  hipFuncSetAttribute((const void*)lstm_kernel,
                      hipFuncAttributeMaxDynamicSharedMemorySize, LSTM_LDS_BYTES);

  prep_kernel <<<67, 256, 0, stream>>>(Wih, Whh, bih, bhh, Wout, Wcb, Woutb, bc);
  stats_kernel<<<64, 256, 0, stream>>>(xin, stats);
  coef_kernel <<<1, 128, 0, stream>>>(stats, Wemb, bemb, ing, inb, eg, eb, A0, A1, Ct);
  lstm_kernel <<<256, 1024, LSTM_LDS_BYTES, stream>>>(xin, A0, A1, Ct, Wcb, bc, Woutb, bout,
                                                      outy, hout, cout);
  ostats_kernel<<<256, 256, 0, stream>>>(outy, ostp);
  ofin_kernel <<<1, 320, 0, stream>>>(ostp, og, ob, sc, sh);
  onorm_kernel<<<2048, 256, 0, stream>>>(outy, sc, sh);
}

// Round 7
// 287.423 us; speedup vs baseline: 3.5473x; 2.5911x over previous
//
#include <hip/hip_runtime.h>
#include <hip/hip_bf16.h>

#define BB 8192
#define TT 64
#define L2E 1.44269504088896f
#define AROW 512                    // acts row stride (shorts): e0[0,128) e1[128,256) h0[256,384) h1[384,512)

typedef __attribute__((ext_vector_type(8))) short bf16x8;
typedef __attribute__((ext_vector_type(4))) short bf16x4;
typedef __attribute__((ext_vector_type(4))) float f32x4;

__device__ __forceinline__ float exp2g(float x) { return __builtin_amdgcn_exp2f(x); }
__device__ __forceinline__ float rcpg(float x)  { return __builtin_amdgcn_rcpf(x); }
__device__ __forceinline__ short f2bf_s(float x) {
  __hip_bfloat16 b = __float2bfloat16(x);
  return *reinterpret_cast<short*>(&b);
}
__device__ __forceinline__ float bf2f(short v) {
  unsigned u = ((unsigned)(unsigned short)v) << 16;
  return __uint_as_float(u);
}
// granule-swizzled fragment read: acts[row][k], granule kg = k>>3
__device__ __forceinline__ bf16x8 ldfrag(const short* acts, int row, int kg) {
  return *(const bf16x8*)&acts[row * AROW + ((kg ^ (row & 7)) << 3)];
}

// ---- 1. weights -> bf16 A-operand fragments, gate-packed cols, exp2-prescaled ----
// Wcb frag f = mt*8+kt: lane l elem e = s(gate) * Wc[k = kt*32+(l>>4)*8+e][c = gate*128 + j]
//   where mloc = l&15, j = mt*4 + (mloc>>2), gate = mloc&3
__global__ void prep_kernel(const float* __restrict__ Wih, const float* __restrict__ Whh,
                            const float* __restrict__ bih, const float* __restrict__ bhh,
                            const float* __restrict__ Wout,
                            short* __restrict__ Wcb, short* __restrict__ Woutb,
                            float* __restrict__ bc) {
  int idx = blockIdx.x * 256 + threadIdx.x;   // 17152 total
  if (idx < 16384) {
    int l = idx & 63, f = idx >> 6;
    int mt = f >> 3, kt = f & 7;
    int mloc = l & 15;
    int j = mt * 4 + (mloc >> 2);
    int gate = mloc & 3;
    int c = gate * 128 + j;
    int k0 = kt * 32 + ((l >> 4) << 3);
    float s = (gate == 2) ? (2.f * L2E) : (-L2E);
    const float* src = (k0 < 128) ? (Wih + c * 128 + k0) : (Whh + c * 128 + (k0 - 128));
    bf16x8 v;
    #pragma unroll
    for (int e = 0; e < 8; e++) v[e] = f2bf_s(src[e] * s);
    *(bf16x8*)(Wcb + (size_t)idx * 8) = v;
  } else if (idx < 16640) {
    int i2 = idx - 16384;
    int l = i2 & 63, f = i2 >> 6;              // f = kyt
    int k0 = f * 32 + ((l >> 4) << 3);
    int col = l & 15;
    bf16x8 v;
    #pragma unroll
    for (int e = 0; e < 8; e++)
      v[e] = (col < 5) ? f2bf_s(Wout[col * 128 + k0 + e]) : (short)0;
    *(bf16x8*)(Woutb + (size_t)i2 * 8) = v;
  } else {
    int i3 = idx - 16640;
    int gate = i3 >> 7;
    float s = (gate == 2) ? (2.f * L2E) : (-L2E);
    bc[i3] = (bih[i3] + bhh[i3]) * s;
  }
}

// ---- 2. per-t raw input moments over batch ----
__global__ void stats_kernel(const float* __restrict__ x, float* __restrict__ stats) {
  int t = blockIdx.x, tid = threadIdx.x;
  float s0=0, s1=0, s2=0, s3=0, s4=0;
  for (int b = tid; b < BB; b += 256) {
    const float* p = x + ((size_t)b * TT + t) * 2;
    float x0 = p[0], x1 = p[1];
    s0 += x0; s1 += x1; s2 += x0*x0; s3 += x0*x1; s4 += x1*x1;
  }
  __shared__ float red[4][5];
  int lane = tid & 63, w = tid >> 6;
  #pragma unroll
  for (int off = 32; off > 0; off >>= 1) {
    s0 += __shfl_down(s0, off); s1 += __shfl_down(s1, off);
    s2 += __shfl_down(s2, off); s3 += __shfl_down(s3, off); s4 += __shfl_down(s4, off);
  }
  if (lane == 0) { red[w][0]=s0; red[w][1]=s1; red[w][2]=s2; red[w][3]=s3; red[w][4]=s4; }
  __syncthreads();
  if (tid < 5) stats[t*5 + tid] = red[0][tid] + red[1][tid] + red[2][tid] + red[3][tid];
}

// ---- 3. fold input-BN + embed Linear + per-step embed-BN into A0/A1/C ----
__global__ void coef_kernel(const float* __restrict__ stats,
                            const float* __restrict__ Wemb, const float* __restrict__ bemb,
                            const float* __restrict__ ing, const float* __restrict__ inb,
                            const float* __restrict__ eg, const float* __restrict__ eb,
                            float* __restrict__ A0, float* __restrict__ A1, float* __restrict__ Ct) {
  __shared__ float st[64][5];
  __shared__ float glob[4];
  int tid = threadIdx.x;  // 128
  for (int i = tid; i < 320; i += 128) st[i / 5][i % 5] = stats[i];
  __syncthreads();
  if (tid == 0) {
    float S0=0, S1=0, S00=0, S11=0;
    for (int t = 0; t < 64; t++) { S0+=st[t][0]; S1+=st[t][1]; S00+=st[t][2]; S11+=st[t][4]; }
    float inv_n = 1.f / (float)(BB * TT);
    float M0 = S0*inv_n, M1 = S1*inv_n;
    float V0 = S00*inv_n - M0*M0, V1 = S11*inv_n - M1*M1;
    float P0 = rsqrtf(V0 + 1e-5f) * ing[0];
    float P1 = rsqrtf(V1 + 1e-5f) * ing[1];
    glob[0]=P0; glob[1]=P1; glob[2]=inb[0]-M0*P0; glob[3]=inb[1]-M1*P1;
  }
  __syncthreads();
  float P0=glob[0], P1=glob[1], Q0=glob[2], Q1=glob[3];
  int j = tid;
  float w0 = Wemb[j*2], w1 = Wemb[j*2+1];
  float a0 = P0*w0, a1 = P1*w1;
  float cj = Q0*w0 + Q1*w1 + bemb[j];
  float gam = eg[j], bet = eb[j];
  float invB = 1.f / (float)BB;
  for (int t = 0; t < 64; t++) {
    float m0 = st[t][0]*invB, m1 = st[t][1]*invB;
    float v00 = st[t][2]*invB - m0*m0;
    float v01 = st[t][3]*invB - m0*m1;
    float v11 = st[t][4]*invB - m1*m1;
    float mean = a0*m0 + a1*m1 + cj;
    float var  = a0*a0*v00 + 2.f*a0*a1*v01 + a1*a1*v11;
    float G = rsqrtf(var + 1e-5f) * gam;
    A0[t*128 + j] = G * a0;
    A1[t*128 + j] = G * a1;
    Ct[t*128 + j] = G * cj + (bet - mean * G);
  }
}

// ---- 4. transposed-GEMM MFMA recurrence: 256 blocks x 32 rows, 16 waves, 1 barrier/step ----
__launch_bounds__(1024, 1)
__global__ void lstm_kernel(const float* __restrict__ x,
                            const float* __restrict__ A0, const float* __restrict__ A1,
                            const float* __restrict__ Ctab,
                            const short* __restrict__ Wcb, const float* __restrict__ bc,
                            const short* __restrict__ Woutb, const float* __restrict__ bout,
                            float* __restrict__ outy, float* __restrict__ hout,
                            float* __restrict__ cout) {
  __shared__ __align__(16) short acts[32 * AROW];  // 32 KB
  __shared__ __align__(16) float xs[32 * 128];     // 16 KB

  const int tid  = threadIdx.x;
  const int lane = tid & 63;
  const int w    = tid >> 6;        // wave 0..15: M-tiles 2w, 2w+1 (j = 8w..8w+7)
  const int cl   = lane & 15;       // batch col in C / A-frag m-row / B-frag n
  const int lq   = lane >> 4;       // quad: j_local for C rows
  const int er32 = tid >> 5;        // e-writer row 0..31
  const int cq   = tid & 31;        // e-writer half-granule (4 elems)
  const int row0 = blockIdx.x * 32;

  // preload x rows (1024 float4 = 4096 floats)
  ((float4*)xs)[tid] = ((const float4*)(x + (size_t)row0 * 128))[tid];

  // per-lane gate biases: j(mtl) = (2w+mtl)*4 + lq
  float bgs[2][4];
  #pragma unroll
  for (int mtl = 0; mtl < 2; mtl++) {
    int j = (2 * w + mtl) * 4 + lq;
    #pragma unroll
    for (int g = 0; g < 4; g++) bgs[mtl][g] = bc[g * 128 + j];
  }
  const float bov = (cl < 5) ? bout[cl] : 0.f;

  // weights resident: 16 frags = 64 VGPR
  bf16x8 wreg[8][2];
  {
    const bf16x8* wptr = (const bf16x8*)Wcb;
    #pragma unroll
    for (int kt = 0; kt < 8; kt++)
      #pragma unroll
      for (int mtl = 0; mtl < 2; mtl++)
        wreg[kt][mtl] = wptr[(size_t)((2 * w + mtl) * 8 + kt) * 64 + lane];
  }

  __syncthreads();  // xs ready

  // prologue: e(0) -> ebuf0; h(-1)=0 -> hbuf1 (granules 48..63)
  {
    float4 a0 = *(const float4*)(A0 + cq * 4);
    float4 a1 = *(const float4*)(A1 + cq * 4);
    float4 ct = *(const float4*)(Ctab + cq * 4);
    float x0 = xs[er32 * 128], x1 = xs[er32 * 128 + 1];
    bf16x4 v;
    v[0] = f2bf_s(fmaxf(fmaf(a0.x, x0, fmaf(a1.x, x1, ct.x)), 0.f));
    v[1] = f2bf_s(fmaxf(fmaf(a0.y, x0, fmaf(a1.y, x1, ct.y)), 0.f));
    v[2] = f2bf_s(fmaxf(fmaf(a0.z, x0, fmaf(a1.z, x1, ct.z)), 0.f));
    v[3] = f2bf_s(fmaxf(fmaf(a0.w, x0, fmaf(a1.w, x1, ct.w)), 0.f));
    *(bf16x4*)&acts[er32 * AROW + (((cq >> 1) ^ (er32 & 7)) << 3) + (cq & 1) * 4] = v;
    if (tid < 512) {
      int er = tid >> 4, g = 48 + (tid & 15);
      bf16x8 z = (bf16x8)0;
      *(bf16x8*)&acts[er * AROW + ((g ^ (er & 7)) << 3)] = z;
    }
  }
  __syncthreads();

  float cst[2][2] = {{0.f, 0.f}, {0.f, 0.f}};

  #pragma unroll 1
  for (int t = 0; t < TT; t++) {
    const int ebuf = t & 1;
    const int hb_prev = (t + 1) & 1;
    const int hb_cur  = t & 1;
    const bool do_e = (t < TT - 1);

    // issue e(t+1) table/x loads early (finish after MFMA: T14)
    float4 ta0, ta1, tct;
    float ex0 = 0.f, ex1 = 0.f;
    if (do_e) {
      ta0 = *(const float4*)(A0 + (t + 1) * 128 + cq * 4);
      ta1 = *(const float4*)(A1 + (t + 1) * 128 + cq * 4);
      tct = *(const float4*)(Ctab + (t + 1) * 128 + cq * 4);
      ex0 = xs[er32 * 128 + (t + 1) * 2];
      ex1 = xs[er32 * 128 + (t + 1) * 2 + 1];
    }

    // y(t-1) = h(t-1) @ Wout^T (waves 0-1)
    if (w < 2 && t > 0) {
      f32x4 ya = (f32x4){0.f, 0.f, 0.f, 0.f};
      #pragma unroll
      for (int kyt = 0; kyt < 4; kyt++) {
        bf16x8 wo = *(const bf16x8*)(Woutb + (size_t)(kyt * 64 + lane) * 8);
        bf16x8 ah = ldfrag(acts, w * 16 + cl, 32 + hb_prev * 16 + kyt * 4 + lq);
        ya = __builtin_amdgcn_mfma_f32_16x16x32_bf16(ah, wo, ya, 0, 0, 0);
      }
      if (cl < 5) {
        #pragma unroll
        for (int q = 0; q < 4; q++)
          outy[((size_t)(row0 + w * 16 + lq * 4 + q) * TT + (t - 1)) * 5 + cl] = ya[q] + bov;
      }
    }

    // gates^T = Wc(A) x acts(B): full K per wave
    f32x4 acc[2][2];
    #pragma unroll
    for (int mtl = 0; mtl < 2; mtl++) {
      f32x4 binit = (f32x4){bgs[mtl][0], bgs[mtl][1], bgs[mtl][2], bgs[mtl][3]};
      acc[mtl][0] = binit;
      acc[mtl][1] = binit;
    }
    __builtin_amdgcn_s_setprio(1);
    #pragma unroll
    for (int kt = 0; kt < 8; kt++) {
      int kg = (kt < 4) ? (ebuf * 16 + kt * 4 + lq)
                        : (32 + hb_prev * 16 + (kt - 4) * 4 + lq);
      bf16x8 b0 = ldfrag(acts, cl, kg);
      bf16x8 b1 = ldfrag(acts, 16 + cl, kg);
      #pragma unroll
      for (int mtl = 0; mtl < 2; mtl++) {
        acc[mtl][0] = __builtin_amdgcn_mfma_f32_16x16x32_bf16(wreg[kt][mtl], b0, acc[mtl][0], 0, 0, 0);
        acc[mtl][1] = __builtin_amdgcn_mfma_f32_16x16x32_bf16(wreg[kt][mtl], b1, acc[mtl][1], 0, 0, 0);
      }
    }
    __builtin_amdgcn_s_setprio(0);

    // lane-local LSTM update: 4 cells (mtl x nt), gates in vector components
    #pragma unroll
    for (int mtl = 0; mtl < 2; mtl++) {
      const int j = (2 * w + mtl) * 4 + lq;
      const int kg2 = 32 + hb_cur * 16 + w;    // j>>3 == w
      #pragma unroll
      for (int nt = 0; nt < 2; nt++) {
        float Ei = exp2g(acc[mtl][nt][0]);     // e^{-i}
        float Ef = exp2g(acc[mtl][nt][1]);     // e^{-f}
        float Eg = exp2g(acc[mtl][nt][2]);     // e^{2g}
        float Eo = exp2g(acc[mtl][nt][3]);     // e^{-o}
        float ig = (Eg - 1.f) * rcpg((1.f + Ei) * (1.f + Eg));
        float fv = rcpg(1.f + Ef);
        float cn = fmaf(fv, cst[mtl][nt], ig);
        cst[mtl][nt] = cn;
        float Ec = exp2g(cn * (2.f * L2E));
        float hn = (Ec - 1.f) * rcpg((1.f + Eo) * (1.f + Ec));
        int row = nt * 16 + cl;
        acts[row * AROW + ((kg2 ^ (row & 7)) << 3) + (j & 7)] = f2bf_s(hn);
        if (t == TT - 1) {
          hout[(size_t)(row0 + row) * 128 + j] = hn;
          cout[(size_t)(row0 + row) * 128 + j] = cn;
        }
      }
    }

    // finish e(t+1) -> ebuf^1
    if (do_e) {
      bf16x4 v;
      v[0] = f2bf_s(fmaxf(fmaf(ta0.x, ex0, fmaf(ta1.x, ex1, tct.x)), 0.f));
      v[1] = f2bf_s(fmaxf(fmaf(ta0.y, ex0, fmaf(ta1.y, ex1, tct.y)), 0.f));
      v[2] = f2bf_s(fmaxf(fmaf(ta0.z, ex0, fmaf(ta1.z, ex1, tct.z)), 0.f));
      v[3] = f2bf_s(fmaxf(fmaf(ta0.w, ex0, fmaf(ta1.w, ex1, tct.w)), 0.f));
      int g = ((t + 1) & 1) * 16 + (cq >> 1);
      *(bf16x4*)&acts[er32 * AROW + ((g ^ (er32 & 7)) << 3) + (cq & 1) * 4] = v;
    }
    __syncthreads();
  }

  // epilogue: y(63)
  if (w < 2) {
    const int hb = (TT - 1) & 1;
    f32x4 ya = (f32x4){0.f, 0.f, 0.f, 0.f};
    #pragma unroll
    for (int kyt = 0; kyt < 4; kyt++) {
      bf16x8 wo = *(const bf16x8*)(Woutb + (size_t)(kyt * 64 + lane) * 8);
      bf16x8 ah = ldfrag(acts, w * 16 + cl, 32 + hb * 16 + kyt * 4 + lq);
      ya = __builtin_amdgcn_mfma_f32_16x16x32_bf16(ah, wo, ya, 0, 0, 0);
    }
    if (cl < 5) {
      #pragma unroll
      for (int q = 0; q < 4; q++)
        outy[((size_t)(row0 + w * 16 + lq * 4 + q) * TT + (TT - 1)) * 5 + cl] = ya[q] + bov;
    }
  }
}

// ---- 5. per-(t,k) output BN partial stats (256 blocks = full chip) ----
__global__ void ostats_kernel(const float* __restrict__ outy, float* __restrict__ ostp) {
  int t = blockIdx.x >> 2, part = blockIdx.x & 3;
  int tid = threadIdx.x;
  float s[5] = {0,0,0,0,0}, s2[5] = {0,0,0,0,0};
  int b0 = part * 2048;
  for (int b = b0 + tid; b < b0 + 2048; b += 256) {
    const float* p = outy + ((size_t)b * TT + t) * 5;
    #pragma unroll
    for (int k = 0; k < 5; k++) { float v = p[k]; s[k] += v; s2[k] += v*v; }
  }
  __shared__ float red[4][10];
  int lane = tid & 63, w = tid >> 6;
  #pragma unroll
  for (int off = 32; off > 0; off >>= 1) {
    #pragma unroll
    for (int k = 0; k < 5; k++) {
      s[k]  += __shfl_down(s[k], off);
      s2[k] += __shfl_down(s2[k], off);
    }
  }
  if (lane == 0) {
    #pragma unroll
    for (int k = 0; k < 5; k++) { red[w][k] = s[k]; red[w][5+k] = s2[k]; }
  }
  __syncthreads();
  if (tid < 10) ostp[blockIdx.x * 10 + tid] = red[0][tid]+red[1][tid]+red[2][tid]+red[3][tid];
}

// ---- 5b. finalize: per-(t,k) scale/shift ----
__global__ void ofin_kernel(const float* __restrict__ ostp,
                            const float* __restrict__ og, const float* __restrict__ ob,
                            float* __restrict__ sc, float* __restrict__ sh) {
  int i = threadIdx.x;               // 320
  if (i >= 320) return;
  int t = i / 5, k = i - t * 5;
  const float invB = 1.f / (float)BB;
  float m  = (ostp[(t*4+0)*10+k]   + ostp[(t*4+1)*10+k]   + ostp[(t*4+2)*10+k]   + ostp[(t*4+3)*10+k]) * invB;
  float s2 = (ostp[(t*4+0)*10+5+k] + ostp[(t*4+1)*10+5+k] + ostp[(t*4+2)*10+5+k] + ostp[(t*4+3)*10+5+k]) * invB;
  float v = s2 - m * m;
  float scale = rsqrtf(v + 1e-5f) * og[k];
  sc[i] = scale;
  sh[i] = ob[k] - m * scale;
}

// ---- 6. normalize outs in place ----
__global__ void onorm_kernel(float* __restrict__ outy, const float* __restrict__ sc,
                             const float* __restrict__ sh) {
  const int N = BB * TT * 5;
  for (int i = blockIdx.x * 256 + threadIdx.x; i < N; i += gridDim.x * 256) {
    int j = i % 320;
    outy[i] = fmaf(outy[i], sc[j], sh[j]);
  }
}

extern "C" void kernel_launch(void* const* d_in, const int* in_sizes, int n_in,
                              void* d_out, int out_size, void* d_ws, size_t ws_size,
                              hipStream_t stream) {
  const float* xin  = (const float*)d_in[0];
  const float* ing  = (const float*)d_in[1];
  const float* inb  = (const float*)d_in[2];
  const float* Wemb = (const float*)d_in[3];
  const float* bemb = (const float*)d_in[4];
  const float* eg   = (const float*)d_in[5];
  const float* eb   = (const float*)d_in[6];
  const float* Wih  = (const float*)d_in[7];
  const float* Whh  = (const float*)d_in[8];
  const float* bih  = (const float*)d_in[9];
  const float* bhh  = (const float*)d_in[10];
  const float* Wout = (const float*)d_in[11];
  const float* bout = (const float*)d_in[12];
  const float* og   = (const float*)d_in[13];
  const float* ob   = (const float*)d_in[14];

  float* ws    = (float*)d_ws;
  float* stats = ws;             // 320
  float* A0    = ws + 1024;      // 8192
  float* A1    = ws + 9216;      // 8192
  float* Ct    = ws + 17408;     // 8192
  float* bc    = ws + 25600;     // 512
  short* Wcb   = (short*)(ws + 26624);   // 131072 shorts (256 KB)
  short* Woutb = (short*)(ws + 92160);   // 2048 shorts (4 KB)
  float* ostp  = ws + 93184;     // 2560
  float* sc    = ws + 95744;     // 320
  float* sh    = ws + 96064;     // 320

  float* outy = (float*)d_out;
  float* hout = outy + (size_t)BB * TT * 5;
  float* cout = hout + (size_t)BB * 128;

  prep_kernel <<<67, 256, 0, stream>>>(Wih, Whh, bih, bhh, Wout, Wcb, Woutb, bc);
  stats_kernel<<<64, 256, 0, stream>>>(xin, stats);
  coef_kernel <<<1, 128, 0, stream>>>(stats, Wemb, bemb, ing, inb, eg, eb, A0, A1, Ct);
  lstm_kernel <<<256, 1024, 0, stream>>>(xin, A0, A1, Ct, Wcb, bc, Woutb, bout,
                                         outy, hout, cout);
  ostats_kernel<<<256, 256, 0, stream>>>(outy, ostp);
  ofin_kernel <<<1, 320, 0, stream>>>(ostp, og, ob, sc, sh);
  onorm_kernel<<<2048, 256, 0, stream>>>(outy, sc, sh);
}